// Round 9
// baseline (346.690 us; speedup 1.0000x reference)
//
#include <hip/hip_runtime.h>
#include <hip/hip_bf16.h>
#include <stdint.h>

typedef __attribute__((ext_vector_type(4))) float f32x4;
typedef __attribute__((ext_vector_type(8))) __bf16 bf16x8;
typedef __attribute__((ext_vector_type(2))) unsigned int u32x2;
typedef __attribute__((ext_vector_type(4))) unsigned int u32x4;

#define N_NODES 16384
#define F_DIM   64
#define BM      128                     // rows per block (8 waves x 16 rows)
#define NF      (N_NODES * F_DIM)       // elements per partial

__device__ inline unsigned cvtpk_bf16(float lo, float hi) {
    unsigned r;
    asm("v_cvt_pk_bf16_f32 %0, %1, %2" : "=v"(r) : "v"(lo), "v"(hi));
    return r;
}
__device__ inline float bf_lo(unsigned u) { union { unsigned v; float f; } c; c.v = u << 16; return c.f; }
__device__ inline float bf_hi(unsigned u) { union { unsigned v; float f; } c; c.v = u & 0xffff0000u; return c.f; }

// ---------------------------------------------------------------------------
// Kernel A: h = input @ W (fp32 compute), stored bf16 in MFMA B-frag layout:
// chunk[(kb*4+ct)*64 + l] (16B) = h[kb*32 + (l>>4)*8 + j][ct*16 + (l&15)]
// ---------------------------------------------------------------------------
__global__ __launch_bounds__(256) void dense_h(const float* __restrict__ inp,
                                               const float* __restrict__ W,
                                               short* __restrict__ hpack) {
    __shared__ float in_lds[64][64];
    __shared__ float wt_lds[64][68];
    const int t = threadIdx.x;
    const int blk = blockIdx.x;

#pragma unroll
    for (int i = 0; i < 4; ++i) {
        int n = i * 256 + t; int row = n >> 4; int c = n & 15;
        f32x4 v = *(const f32x4*)(inp + (size_t)(blk * 64 + row) * 64 + c * 4);
        *(f32x4*)(&in_lds[row][c * 4]) = v;
    }
#pragma unroll
    for (int i = 0; i < 4; ++i) {
        int n = i * 256 + t; int k = n >> 4; int c = n & 15;
        f32x4 v = *(const f32x4*)(W + k * 64 + c * 4);
        wt_lds[c * 4 + 0][k] = v.x; wt_lds[c * 4 + 1][k] = v.y;
        wt_lds[c * 4 + 2][k] = v.z; wt_lds[c * 4 + 3][k] = v.w;
    }
    __syncthreads();

#pragma unroll
    for (int cc = 0; cc < 2; ++cc) {
        int c = cc * 256 + t;
        int kbL = c >> 8; int ct = (c >> 6) & 3; int l = c & 63;
        int f  = ct * 16 + (l & 15);
        int r0 = kbL * 32 + (l >> 4) * 8;
        float acc[8] = {0, 0, 0, 0, 0, 0, 0, 0};
        for (int k = 0; k < 64; k += 4) {
            f32x4 wv = *(const f32x4*)(&wt_lds[f][k]);
#pragma unroll
            for (int j = 0; j < 8; ++j) {
                f32x4 iv = *(const f32x4*)(&in_lds[r0 + j][k]);
                acc[j] += iv.x * wv.x + iv.y * wv.y + iv.z * wv.z + iv.w * wv.w;
            }
        }
        u32x4 w4 = {cvtpk_bf16(acc[0], acc[1]), cvtpk_bf16(acc[2], acc[3]),
                    cvtpk_bf16(acc[4], acc[5]), cvtpk_bf16(acc[6], acc[7])};
        int kb = blk * 2 + kbL;
        *(u32x4*)(hpack + ((size_t)(kb * 4 + ct) * 64 + l) * 8) = w4;
    }
}

// ---------------------------------------------------------------------------
// Kernel B: partial[sp] = adj[:, k-range] @ h[k-range, :], FUSED reduction:
// after writing its packed-bf16 partial, each block increments cnt[rb]
// (device-scope, release-fenced). The 4th finisher re-reads ALL FOUR
// partial slices in fixed sp order (bit-deterministic regardless of which
// block reduces) from L2/L3-hot lines and writes out + bias.
// Main loop = R5/R7 structure verbatim.
// ---------------------------------------------------------------------------
__global__ __launch_bounds__(512, 4) void spmm_adj(const float* __restrict__ adj,
                                                   const short* __restrict__ hp,
                                                   unsigned short* __restrict__ partial,
                                                   int* __restrict__ cnt,
                                                   float* __restrict__ outp,
                                                   const float* __restrict__ bias,
                                                   int kspan, int nsp) {
    const int rb = blockIdx.x;
    const int sp = blockIdx.y;
    const int k0 = sp * kspan;
    const int iters = kspan >> 6;          // K-step 64
    const int t  = threadIdx.x;
    const int wv = t >> 6;                 // 0..7
    const int ln = t & 63;

    __shared__ short At[2][BM * 64];       // bf16, XOR-swizzled, 16KB each
    __shared__ int isLast;

    const size_t rowbase = (size_t)(rb * BM) * N_NODES;
    const int srow = t >> 4;               // 0..31 staging row group
    const int scol = t & 15;               // 16B chunk within 256B row

    auto ldA = [&](int tt, f32x4* rv) {    // BM x 64 fp32 tile, 256B/row over 16 lanes
        const float* base = adj + rowbase + (size_t)(k0 + tt * 64);
#pragma unroll
        for (int i = 0; i < 4; ++i) {
            int row = i * 32 + srow;
            rv[i] = __builtin_nontemporal_load(
                (const f32x4*)(base + (size_t)row * N_NODES + scol * 4));
        }
    };
    auto stA = [&](int buf, const f32x4* rv) {
#pragma unroll
        for (int i = 0; i < 4; ++i) {
            int row = i * 32 + srow;
            u32x2 w = {cvtpk_bf16(rv[i].x, rv[i].y), cvtpk_bf16(rv[i].z, rv[i].w)};
            int byte = row * 128 + ((scol * 8) ^ ((row & 7) << 4));
            *(u32x2*)((char*)At[buf] + byte) = w;
        }
    };

    f32x4 acc[4] = {{0,0,0,0},{0,0,0,0},{0,0,0,0},{0,0,0,0}};
    const int abase = (wv * 16 + (ln & 15)) * 128;
    const int aswz  = (ln & 7) << 4;
    const int koff  = (ln >> 4) * 16;

    f32x4 rv[4];
    ldA(0, rv);
    stA(0, rv);

    for (int tt = 0; tt < iters; ++tt) {
        const int cur = tt & 1;
        const bool more = (tt + 1 < iters);
        if (more) ldA(tt + 1, rv);                     // prefetch next A tile
        asm volatile("s_waitcnt lgkmcnt(0)" ::: "memory");
        __builtin_amdgcn_s_barrier();                  // raw barrier: no vmcnt drain
#pragma unroll
        for (int ks2 = 0; ks2 < 2; ++ks2) {
            bf16x8 a = *(const bf16x8*)((const char*)At[cur] + abase + ((ks2 * 64 + koff) ^ aswz));
            const short* hbase = hp + ((size_t)((k0 >> 5) + tt * 2 + ks2) * 4) * 512;
#pragma unroll
            for (int ct = 0; ct < 4; ++ct) {
                bf16x8 b = *(const bf16x8*)(hbase + ct * 512 + ln * 8);   // L2-hot
                acc[ct] = __builtin_amdgcn_mfma_f32_16x16x32_bf16(a, b, acc[ct], 0, 0, 0);
            }
        }
        if (more) stA(cur ^ 1, rv);
    }

    // ---- write packed bf16 partial (coalesced 8B/lane) ----
    {
        unsigned short* po = partial + (size_t)sp * NF
                           + ((size_t)(rb * 8 + wv) * 4) * 256 + ln * 4;
#pragma unroll
        for (int ct = 0; ct < 4; ++ct) {
            u32x2 w = {cvtpk_bf16(acc[ct][0], acc[ct][1]),
                       cvtpk_bf16(acc[ct][2], acc[ct][3])};
            *(u32x2*)(po + ct * 256) = w;
        }
    }

    // ---- last-block-done fused reduction ----
    __threadfence();                                    // release: partials visible device-wide
    if (t == 0) {
        int old = atomicAdd(&cnt[rb], 1);
        isLast = (old == nsp - 1);
    }
    __syncthreads();
    if (!isLast) return;
    __threadfence();                                    // acquire: invalidate stale L2 lines

    // this block reduces rb's slice: 8192 elems, 16 per thread, fixed sp order
    float s[16];
#pragma unroll
    for (int e = 0; e < 16; ++e) s[e] = 0.f;
    for (int i = 0; i < nsp; ++i) {
        const unsigned short* p = partial + (size_t)i * NF + (size_t)rb * 8192 + t * 16;
        u32x4 w0 = *(const u32x4*)(p);
        u32x4 w1 = *(const u32x4*)(p + 8);
        s[0]  += bf_lo(w0.x); s[1]  += bf_hi(w0.x);
        s[2]  += bf_lo(w0.y); s[3]  += bf_hi(w0.y);
        s[4]  += bf_lo(w0.z); s[5]  += bf_hi(w0.z);
        s[6]  += bf_lo(w0.w); s[7]  += bf_hi(w0.w);
        s[8]  += bf_lo(w1.x); s[9]  += bf_hi(w1.x);
        s[10] += bf_lo(w1.y); s[11] += bf_hi(w1.y);
        s[12] += bf_lo(w1.z); s[13] += bf_hi(w1.z);
        s[14] += bf_lo(w1.w); s[15] += bf_hi(w1.w);
    }
#pragma unroll
    for (int e = 0; e < 16; ++e) {
        int q   = t * 16 + e;                // index within rb slice
        int j   = q & 3;
        int lnq = (q >> 2) & 63;
        int ctq = (q >> 8) & 3;
        int wvq = q >> 10;
        int row = rb * BM + wvq * 16 + (lnq >> 4) * 4 + j;
        int col = ctq * 16 + (lnq & 15);
        outp[(size_t)row * F_DIM + col] = s[e] + bias[col];
    }
}

// ---------------------------------------------------------------------------
// Kernel C (fallback only): out = sum_sp packed partial + bias
// ---------------------------------------------------------------------------
__global__ __launch_bounds__(256) void reduce_add(const unsigned short* __restrict__ part,
                                                  const float* __restrict__ bias,
                                                  float* __restrict__ out, int nsp) {
    int g = blockIdx.x * 256 + threadIdx.x;            // 0 .. NF/4-1, 4 values each
    int ln = g & 63, ct = (g >> 6) & 3, wvr = (g >> 8) & 7, rb = g >> 11;
    f32x4 s = {0, 0, 0, 0};
    for (int i = 0; i < nsp; ++i) {
        u32x2 w = *(const u32x2*)(part + (size_t)i * NF + (size_t)g * 4);
        s.x += bf_lo(w.x); s.y += bf_hi(w.x);
        s.z += bf_lo(w.y); s.w += bf_hi(w.y);
    }
    const int row0 = rb * BM + wvr * 16 + (ln >> 4) * 4;
    const int col  = ct * 16 + (ln & 15);
    const float bv = bias[col];
#pragma unroll
    for (int j = 0; j < 4; ++j)
        out[(size_t)(row0 + j) * F_DIM + col] = s[j] + bv;
}

extern "C" void kernel_launch(void* const* d_in, const int* in_sizes, int n_in,
                              void* d_out, int out_size, void* d_ws, size_t ws_size,
                              hipStream_t stream) {
    const float* inp = (const float*)d_in[0];
    const float* adj = (const float*)d_in[1];
    const float* W   = (const float*)d_in[2];
    const float* b   = (const float*)d_in[3];
    float* out = (float*)d_out;

    char*  ws = (char*)d_ws;
    const size_t HP = (size_t)NF * sizeof(short);           // 2 MB packed bf16 h
    const size_t PB = (size_t)NF * sizeof(unsigned short);  // 2 MB per bf16 partial
    short* hpack = (short*)ws;
    unsigned short* partial = (unsigned short*)(ws + HP);
    int* cnt = (int*)(ws + HP + 4 * PB);                    // 128 x 4B counters

    dense_h<<<N_NODES / 64, 256, 0, stream>>>(inp, W, hpack);

    if (ws_size >= HP + 4 * PB + (N_NODES / BM) * sizeof(int)) {
        hipMemsetAsync(cnt, 0, (N_NODES / BM) * sizeof(int), stream);
        dim3 g(N_NODES / BM, 4);             // 512 blocks = 2/CU, one residency round
        spmm_adj<<<g, 512, 0, stream>>>(adj, hpack, partial, cnt, out, b, N_NODES / 4, 4);
    } else if (ws_size >= HP + PB + (N_NODES / BM) * sizeof(int)) {
        int* cnt1 = (int*)(ws + HP + PB);
        hipMemsetAsync(cnt1, 0, (N_NODES / BM) * sizeof(int), stream);
        dim3 g(N_NODES / BM, 1);
        spmm_adj<<<g, 512, 0, stream>>>(adj, hpack, partial, cnt1, out, b, N_NODES, 1);
    } else {
        dim3 g(N_NODES / BM, 1);
        hipMemsetAsync((int*)(ws + HP + PB - 512), 0, 512, stream);
        spmm_adj<<<g, 512, 0, stream>>>(adj, hpack, partial,
                                        (int*)(ws + HP + PB - 512), out, b, N_NODES, 1);
    }
}

// Round 10
// 204.705 us; speedup vs baseline: 1.6936x; 1.6936x over previous
//
#include <hip/hip_runtime.h>
#include <hip/hip_bf16.h>
#include <stdint.h>

typedef __attribute__((ext_vector_type(4))) float f32x4;
typedef __attribute__((ext_vector_type(8))) __bf16 bf16x8;
typedef __attribute__((ext_vector_type(2))) unsigned int u32x2;
typedef __attribute__((ext_vector_type(4))) unsigned int u32x4;

#define N_NODES 16384
#define F_DIM   64
#define BM      128                     // rows per block (8 waves x 16 rows)
#define NF      (N_NODES * F_DIM)       // elements per partial

__device__ inline unsigned cvtpk_bf16(float lo, float hi) {
    unsigned r;
    asm("v_cvt_pk_bf16_f32 %0, %1, %2" : "=v"(r) : "v"(lo), "v"(hi));
    return r;
}
__device__ inline float bf_lo(unsigned u) { union { unsigned v; float f; } c; c.v = u << 16; return c.f; }
__device__ inline float bf_hi(unsigned u) { union { unsigned v; float f; } c; c.v = u & 0xffff0000u; return c.f; }

// ---------------------------------------------------------------------------
// Kernel A: h = input @ W (fp32 compute), stored bf16 in MFMA B-frag layout:
// chunk[(kb*4+ct)*64 + l] (16B) = h[kb*32 + (l>>4)*8 + j][ct*16 + (l&15)]
// ---------------------------------------------------------------------------
__global__ __launch_bounds__(256) void dense_h(const float* __restrict__ inp,
                                               const float* __restrict__ W,
                                               short* __restrict__ hpack) {
    __shared__ float in_lds[64][64];
    __shared__ float wt_lds[64][68];
    const int t = threadIdx.x;
    const int blk = blockIdx.x;

#pragma unroll
    for (int i = 0; i < 4; ++i) {
        int n = i * 256 + t; int row = n >> 4; int c = n & 15;
        f32x4 v = *(const f32x4*)(inp + (size_t)(blk * 64 + row) * 64 + c * 4);
        *(f32x4*)(&in_lds[row][c * 4]) = v;
    }
#pragma unroll
    for (int i = 0; i < 4; ++i) {
        int n = i * 256 + t; int k = n >> 4; int c = n & 15;
        f32x4 v = *(const f32x4*)(W + k * 64 + c * 4);
        wt_lds[c * 4 + 0][k] = v.x; wt_lds[c * 4 + 1][k] = v.y;
        wt_lds[c * 4 + 2][k] = v.z; wt_lds[c * 4 + 3][k] = v.w;
    }
    __syncthreads();

#pragma unroll
    for (int cc = 0; cc < 2; ++cc) {
        int c = cc * 256 + t;
        int kbL = c >> 8; int ct = (c >> 6) & 3; int l = c & 63;
        int f  = ct * 16 + (l & 15);
        int r0 = kbL * 32 + (l >> 4) * 8;
        float acc[8] = {0, 0, 0, 0, 0, 0, 0, 0};
        for (int k = 0; k < 64; k += 4) {
            f32x4 wv = *(const f32x4*)(&wt_lds[f][k]);
#pragma unroll
            for (int j = 0; j < 8; ++j) {
                f32x4 iv = *(const f32x4*)(&in_lds[r0 + j][k]);
                acc[j] += iv.x * wv.x + iv.y * wv.y + iv.z * wv.z + iv.w * wv.w;
            }
        }
        u32x4 w4 = {cvtpk_bf16(acc[0], acc[1]), cvtpk_bf16(acc[2], acc[3]),
                    cvtpk_bf16(acc[4], acc[5]), cvtpk_bf16(acc[6], acc[7])};
        int kb = blk * 2 + kbL;
        *(u32x4*)(hpack + ((size_t)(kb * 4 + ct) * 64 + l) * 8) = w4;
    }
}

// ---------------------------------------------------------------------------
// Kernel B: partial[sp] = adj[:, k-range] @ h[k-range, :]
// R7 structure verbatim (block-wide coalesced LDS staging, XOR swizzle, raw
// s_barrier + lgkmcnt(0), inline B loads, 1-deep A prefetch, nontemporal
// adj, BM=128/BK=64, 512 thr, 2 blocks/CU; packed bf16 partial epilogue).
// Only change: partial stores are nontemporal (write-once stream; keeps L2
// clean for the hp B-fragments).
// ---------------------------------------------------------------------------
__global__ __launch_bounds__(512, 4) void spmm_adj(const float* __restrict__ adj,
                                                   const short* __restrict__ hp,
                                                   void* __restrict__ dst,
                                                   const float* __restrict__ bias,
                                                   int kspan, int direct) {
    const int rb = blockIdx.x;
    const int sp = blockIdx.y;
    const int k0 = sp * kspan;
    const int iters = kspan >> 6;          // K-step 64
    const int t  = threadIdx.x;
    const int wv = t >> 6;                 // 0..7
    const int ln = t & 63;

    __shared__ short At[2][BM * 64];       // bf16, XOR-swizzled, 16KB each

    const size_t rowbase = (size_t)(rb * BM) * N_NODES;
    const int srow = t >> 4;               // 0..31 staging row group
    const int scol = t & 15;               // 16B chunk within 256B row

    auto ldA = [&](int tt, f32x4* rv) {    // BM x 64 fp32 tile, 256B/row over 16 lanes
        const float* base = adj + rowbase + (size_t)(k0 + tt * 64);
#pragma unroll
        for (int i = 0; i < 4; ++i) {
            int row = i * 32 + srow;
            rv[i] = __builtin_nontemporal_load(
                (const f32x4*)(base + (size_t)row * N_NODES + scol * 4));
        }
    };
    auto stA = [&](int buf, const f32x4* rv) {
#pragma unroll
        for (int i = 0; i < 4; ++i) {
            int row = i * 32 + srow;
            u32x2 w = {cvtpk_bf16(rv[i].x, rv[i].y), cvtpk_bf16(rv[i].z, rv[i].w)};
            int byte = row * 128 + ((scol * 8) ^ ((row & 7) << 4));
            *(u32x2*)((char*)At[buf] + byte) = w;
        }
    };

    f32x4 acc[4] = {{0,0,0,0},{0,0,0,0},{0,0,0,0},{0,0,0,0}};
    const int abase = (wv * 16 + (ln & 15)) * 128;
    const int aswz  = (ln & 7) << 4;
    const int koff  = (ln >> 4) * 16;

    f32x4 rv[4];
    ldA(0, rv);
    stA(0, rv);

    for (int tt = 0; tt < iters; ++tt) {
        const int cur = tt & 1;
        const bool more = (tt + 1 < iters);
        if (more) ldA(tt + 1, rv);                     // prefetch next A tile
        asm volatile("s_waitcnt lgkmcnt(0)" ::: "memory");
        __builtin_amdgcn_s_barrier();                  // raw barrier: no vmcnt drain
#pragma unroll
        for (int ks2 = 0; ks2 < 2; ++ks2) {
            bf16x8 a = *(const bf16x8*)((const char*)At[cur] + abase + ((ks2 * 64 + koff) ^ aswz));
            const short* hbase = hp + ((size_t)((k0 >> 5) + tt * 2 + ks2) * 4) * 512;
#pragma unroll
            for (int ct = 0; ct < 4; ++ct) {
                bf16x8 b = *(const bf16x8*)(hbase + ct * 512 + ln * 8);   // L2-hot
                acc[ct] = __builtin_amdgcn_mfma_f32_16x16x32_bf16(a, b, acc[ct], 0, 0, 0);
            }
        }
        if (more) stA(cur ^ 1, rv);
    }

    if (direct) {
        // single-pass fallback: fp32 out with bias; C layout col=ln&15, row=(ln>>4)*4+j
        float* o = (float*)dst;
        const int orow0 = rb * BM + wv * 16 + (ln >> 4) * 4;
        const int col   = ln & 15;
#pragma unroll
        for (int ct = 0; ct < 4; ++ct)
#pragma unroll
            for (int j = 0; j < 4; ++j)
                o[(size_t)(orow0 + j) * F_DIM + ct * 16 + col] = acc[ct][j] + bias[ct * 16 + col];
    } else {
        // packed bf16 partial: element (rb,wv,ct,ln,j) at off ((((rb*8+wv)*4+ct)*64)+ln)*4 + j
        unsigned short* po = (unsigned short*)dst + (size_t)sp * NF
                           + ((size_t)(rb * 8 + wv) * 4) * 256 + ln * 4;
#pragma unroll
        for (int ct = 0; ct < 4; ++ct) {
            u32x2 w = {cvtpk_bf16(acc[ct][0], acc[ct][1]),
                       cvtpk_bf16(acc[ct][2], acc[ct][3])};
            __builtin_nontemporal_store(w, (u32x2*)(po + ct * 256));   // write-once stream
        }
    }
}

// ---------------------------------------------------------------------------
// Kernel C: out = sum_sp packed_bf16_partial[sp] + bias  (does the scatter)
// ---------------------------------------------------------------------------
__global__ __launch_bounds__(256) void reduce_add(const unsigned short* __restrict__ part,
                                                  const float* __restrict__ bias,
                                                  float* __restrict__ out, int nsp) {
    int g = blockIdx.x * 256 + threadIdx.x;            // 0 .. NF/4-1, 4 values each
    int ln = g & 63, ct = (g >> 6) & 3, wvr = (g >> 8) & 7, rb = g >> 11;
    f32x4 s = {0, 0, 0, 0};
    for (int i = 0; i < nsp; ++i) {
        u32x2 w = __builtin_nontemporal_load(
            (const u32x2*)(part + (size_t)i * NF + (size_t)g * 4));
        s.x += bf_lo(w.x); s.y += bf_hi(w.x);
        s.z += bf_lo(w.y); s.w += bf_hi(w.y);
    }
    const int row0 = rb * BM + wvr * 16 + (ln >> 4) * 4;
    const int col  = ct * 16 + (ln & 15);
    const float bv = bias[col];
#pragma unroll
    for (int j = 0; j < 4; ++j)
        __builtin_nontemporal_store(s[j] + bv,
            out + (size_t)(row0 + j) * F_DIM + col);
}

extern "C" void kernel_launch(void* const* d_in, const int* in_sizes, int n_in,
                              void* d_out, int out_size, void* d_ws, size_t ws_size,
                              hipStream_t stream) {
    const float* inp = (const float*)d_in[0];
    const float* adj = (const float*)d_in[1];
    const float* W   = (const float*)d_in[2];
    const float* b   = (const float*)d_in[3];
    float* out = (float*)d_out;

    char*  ws = (char*)d_ws;
    const size_t HP = (size_t)NF * sizeof(short);        // 2 MB packed bf16 h
    short* hpack = (short*)ws;
    unsigned short* partial = (unsigned short*)(ws + HP);
    const size_t PB = (size_t)NF * sizeof(unsigned short);  // 2 MB per bf16 partial

    dense_h<<<N_NODES / 64, 256, 0, stream>>>(inp, W, hpack);

    if (ws_size >= HP + 4 * PB) {
        dim3 g(N_NODES / BM, 4);             // 512 blocks = 2/CU, one residency round
        spmm_adj<<<g, 512, 0, stream>>>(adj, hpack, partial, nullptr, N_NODES / 4, 0);
        reduce_add<<<NF / 1024, 256, 0, stream>>>(partial, b, out, 4);
    } else if (ws_size >= HP + PB) {
        dim3 g(N_NODES / BM, 1);
        spmm_adj<<<g, 512, 0, stream>>>(adj, hpack, partial, nullptr, N_NODES, 0);
        reduce_add<<<NF / 1024, 256, 0, stream>>>(partial, b, out, 1);
    } else {
        dim3 g(N_NODES / BM, 1);
        spmm_adj<<<g, 512, 0, stream>>>(adj, hpack, out, b, N_NODES, 1);
    }
}